// Round 10
// baseline (350.697 us; speedup 1.0000x reference)
//
#include <hip/hip_runtime.h>
#include <hip/hip_bf16.h>

// Problem constants (fixed by the reference)
#define NN 50000
#define NE 800000
#define NG 64
#define OUTD 768

#define G1B ((NN + 63) / 64)        // 782 gemm blocks (64 rows/block)
#define SSEG 64                     // edge segments
#define TTL 4                       // node tiles (packed u16 counters, 25 KB)
#define ESEG (NE / SSEG)            // 12500 edges / segment
#define NTL (NN / TTL)              // 12500 nodes / tile
#define HRB (SSEG * TTL)            // 256 hist-rank blocks
#define WB 16                       // prep: frag-table blocks
#define MAXB 128                    // prep: max-reduce blocks
#define NB 196                      // mid_kernel blocks (co-resident, 256 thr)

// frag-table entry counts (uint4 each)
#define W1E 2048                    // (128/32)*(128/16)*64
#define W2E 1024                    // (128/32)*(64/16)*64
#define W3E 256                     // (64/32)*(32/16)*64

// bf16 helpers: storage is ushort, math is fp32 (RTN-even on store)
__device__ __forceinline__ float bflo(unsigned int u) { return __uint_as_float(u << 16); }
__device__ __forceinline__ float bfhi(unsigned int u) { return __uint_as_float(u & 0xffff0000u); }
__device__ __forceinline__ unsigned short f2bf(float f) {
    unsigned int u = __float_as_uint(f);
    return (unsigned short)((u + 0x7fffu + ((u >> 16) & 1u)) >> 16);
}
__device__ __forceinline__ unsigned int pack2bf(float lo, float hi) {
    return (unsigned int)f2bf(lo) | ((unsigned int)f2bf(hi) << 16);
}

typedef __attribute__((ext_vector_type(8))) short bf16x8;
typedef __attribute__((ext_vector_type(4))) float f32x4;
union FragU { uint4 u4; bf16x8 v; };

// ---------------------------------------------------------------------------
// prep: build bf16 B-fragment tables for W1/W2/W3 (once) + wmax = max(ea).
// Frag layout (m89-verified by R9 pass): entry (kc*NCT+ct)*64+lane holds
// lane's 8 bf16 B values: n=lane&15 col, k=quad*8+j.
__global__ __launch_bounds__(256) void prep_kernel(const float* __restrict__ W1,
                                                   const float* __restrict__ W2,
                                                   const float* __restrict__ W3,
                                                   uint4* __restrict__ f1,
                                                   uint4* __restrict__ f2,
                                                   uint4* __restrict__ f3,
                                                   const float* __restrict__ ea,
                                                   unsigned int* wmax) {
    const int b = blockIdx.x;
    if (b < WB) {
        for (int q = b * 256 + threadIdx.x; q < W1E + W2E + W3E; q += WB * 256) {
            const float* W; uint4* F; int N, qq;
            if (q < W1E) { W = W1; F = f1; N = 128; qq = q; }
            else if (q < W1E + W2E) { W = W2; F = f2; N = 64; qq = q - W1E; }
            else { W = W3; F = f3; N = 32; qq = q - W1E - W2E; }
            int lane = qq & 63, fi = qq >> 6;
            int NCT = N / 16, ct = fi % NCT, kc = fi / NCT;
            int col = ct * 16 + (lane & 15);
            int kb = kc * 32 + ((lane >> 4) << 3);
            uint4 w;
            w.x = pack2bf(W[(size_t)(kb + 0) * N + col], W[(size_t)(kb + 1) * N + col]);
            w.y = pack2bf(W[(size_t)(kb + 2) * N + col], W[(size_t)(kb + 3) * N + col]);
            w.z = pack2bf(W[(size_t)(kb + 4) * N + col], W[(size_t)(kb + 5) * N + col]);
            w.w = pack2bf(W[(size_t)(kb + 6) * N + col], W[(size_t)(kb + 7) * N + col]);
            F[qq] = w;
        }
    } else {
        __shared__ float red[256];
        const int bb = b - WB;
        float m = 0.0f;
        for (int i = bb * 256 + threadIdx.x; i < NE; i += MAXB * 256)
            m = fmaxf(m, ea[i]);
        red[threadIdx.x] = m;
        __syncthreads();
        for (int off = 128; off > 0; off >>= 1) {
            if (threadIdx.x < off)
                red[threadIdx.x] = fmaxf(red[threadIdx.x], red[threadIdx.x + off]);
            __syncthreads();
        }
        if (threadIdx.x == 0) atomicMax(wmax, __float_as_uint(red[0]));
    }
}

// ---------------------------------------------------------------------------
// LDS-free MFMA GEMM: Y(bf16) = X @ W via precomputed frag table.
// C/D layout: col=lane&15, row=quad*4+reg  [m89-verified].
template <int K, int N, typename TX>
__device__ __forceinline__ void mfma_gemm_tbl(const TX* __restrict__ X,
                                              const uint4* __restrict__ ftab,
                                              unsigned short* __restrict__ Y,
                                              int nRows, int bx) {
    constexpr int NCT = N / 16;
    constexpr int KS = K / 32;
    const int tid = threadIdx.x;
    const int lane = tid & 63;
    const int wv = tid >> 6;
    const int m = lane & 15;
    const int quad = lane >> 4;
    const int row = bx * 64 + wv * 16 + m;
    const bool rowok = row < nRows;
    const TX* xr = X + (size_t)(rowok ? row : 0) * K;

    f32x4 acc[NCT];
#pragma unroll
    for (int ct = 0; ct < NCT; ++ct) acc[ct] = (f32x4){0.f, 0.f, 0.f, 0.f};

#pragma unroll
    for (int kc = 0; kc < KS; ++kc) {
        const int k0 = kc * 32 + quad * 8;
        FragU a;
        if constexpr (sizeof(TX) == 4) {   // fp32 X -> cvt to bf16
            float4 a0 = make_float4(0.f, 0.f, 0.f, 0.f), a1 = a0;
            if (rowok) {
                a0 = *(const float4*)(xr + k0);
                a1 = *(const float4*)(xr + k0 + 4);
            }
            a.u4 = make_uint4(pack2bf(a0.x, a0.y), pack2bf(a0.z, a0.w),
                              pack2bf(a1.x, a1.y), pack2bf(a1.z, a1.w));
        } else {
            a.u4 = rowok ? *(const uint4*)(xr + k0) : make_uint4(0, 0, 0, 0);
        }
#pragma unroll
        for (int ct = 0; ct < NCT; ++ct) {
            FragU b;
            b.u4 = ftab[(kc * NCT + ct) * 64 + lane];
            acc[ct] = __builtin_amdgcn_mfma_f32_16x16x32_bf16(a.v, b.v, acc[ct], 0, 0, 0);
        }
    }

    const int orowb = bx * 64 + wv * 16 + quad * 4;
#pragma unroll
    for (int ct = 0; ct < NCT; ++ct) {
        int col = ct * 16 + m;
#pragma unroll
        for (int r = 0; r < 4; ++r) {
            int orow = orowb + r;
            if (orow < nRows) Y[(size_t)orow * N + col] = f2bf(acc[ct][r]);
        }
    }
}

template <int K, int N, typename TX>
__global__ __launch_bounds__(256) void mfma_gemm_kernel(const TX* __restrict__ X,
                                                        const uint4* __restrict__ ftab,
                                                        unsigned short* __restrict__ Y,
                                                        int nRows) {
    mfma_gemm_tbl<K, N>(X, ftab, Y, nRows, blockIdx.x);
}

// ---------------------------------------------------------------------------
// fused1: [0,G1B) gemm1 (x fp32 @ W1frag -> bf16, LDS-free); rest: hist-rank
// counting (TTL=4) with packed u16-pair LDS counters (no global atomics).
__global__ __launch_bounds__(256) void fused1_kernel(const float* __restrict__ x,
                                                     const uint4* __restrict__ f1,
                                                     unsigned short* __restrict__ bufA,
                                                     const int* __restrict__ dst,
                                                     int* __restrict__ rank,
                                                     unsigned short* __restrict__ pcnt) {
    extern __shared__ unsigned int lcnt[];   // NTL/2 u32 = 25 KB (u16 pairs)
    const int b = blockIdx.x;
    if (b < G1B) {
        mfma_gemm_tbl<128, 128>(x, f1, bufA, NN, b);
    } else {
        const int b2 = b - G1B;          // 0..HRB-1
        const int seg = b2 >> 2;         // TTL == 4
        const int tile = b2 & 3;
        for (int i = threadIdx.x; i < NTL / 2; i += 256) lcnt[i] = 0;
        __syncthreads();
        const int base = seg * ESEG;
        const int nlo = tile * NTL;
        for (int e = base + threadIdx.x; e < base + ESEG; e += 256) {
            int d = dst[e] - nlo;
            if ((unsigned)d < (unsigned)NTL) {
                unsigned int add = (d & 1) ? 0x10000u : 1u;
                unsigned int old = atomicAdd(&lcnt[d >> 1], add);
                rank[e] = (int)((old >> ((d & 1) * 16)) & 0xffffu);
            }
        }
        __syncthreads();
        // dump u16 counts (pairs) — nlo even, NN even -> 4B aligned
        unsigned int* prow32 = (unsigned int*)(pcnt + (size_t)seg * NN + nlo);
        for (int i = threadIdx.x; i < NTL / 2; i += 256) prow32[i] = lcnt[i];
    }
}

// ---------------------------------------------------------------------------
// Grid barrier: NB blocks (<= CU count, no LDS pressure) are co-resident.
__device__ __forceinline__ void gridbar(unsigned int* bar, unsigned int target) {
    __syncthreads();
    if (threadIdx.x == 0) {
        __hip_atomic_fetch_add(bar, 1u, __ATOMIC_ACQ_REL, __HIP_MEMORY_SCOPE_AGENT);
        while (__hip_atomic_load(bar, __ATOMIC_ACQUIRE, __HIP_MEMORY_SCOPE_AGENT) < target)
            __builtin_amdgcn_s_sleep(2);
    }
    __syncthreads();
}

// mid: comb -> scan -> scat -> deg -> coef, one launch, spin barriers.
// Thread t of block b owns node n = b*256+t throughout.
__global__ __launch_bounds__(256) void mid_kernel(unsigned short* __restrict__ pcnt,
                                                  int* __restrict__ rowptr,
                                                  int* __restrict__ blocksum,
                                                  const int* __restrict__ src,
                                                  const int* __restrict__ dst,
                                                  const float* __restrict__ ea,
                                                  const int* __restrict__ rank,
                                                  int2* __restrict__ epack,
                                                  const unsigned int* __restrict__ wmax,
                                                  float* __restrict__ dinv,
                                                  float* __restrict__ invdeg,
                                                  unsigned int* bar) {
    __shared__ int sh[256];
    const int tid = threadIdx.x;
    const int b = blockIdx.x;
    const int n = b * 256 + tid;

    // ---- phase 1: per-node exclusive prefix over segments (in place) ----
    int run = 0;
    if (n < NN) {
#pragma unroll
        for (int s = 0; s < SSEG; ++s) {
            size_t idx = (size_t)s * NN + n;
            int v = pcnt[idx];
            pcnt[idx] = (unsigned short)run;
            run += v;
        }
    }
    sh[tid] = run;
    __syncthreads();
    for (int off = 128; off > 0; off >>= 1) {
        if (tid < off) sh[tid] += sh[tid + off];
        __syncthreads();
    }
    if (tid == 0) blocksum[b] = sh[0];
    gridbar(bar, NB);

    // ---- phase 2: rowptr = exclusive scan ----
    int v2 = (tid < NB) ? blocksum[tid] : 0;
    __syncthreads();
    sh[tid] = v2;
    __syncthreads();
    for (int off = 1; off < 256; off <<= 1) {
        int t = (tid >= off) ? sh[tid - off] : 0;
        __syncthreads();
        sh[tid] += t;
        __syncthreads();
    }
    const int blockoff = (b > 0) ? sh[b - 1] : 0;
    if (b == 0 && tid == 0) rowptr[NN] = sh[NB - 1];
    __syncthreads();
    sh[tid] = run;
    __syncthreads();
    for (int off = 1; off < 256; off <<= 1) {
        int t = (tid >= off) ? sh[tid - off] : 0;
        __syncthreads();
        sh[tid] += t;
        __syncthreads();
    }
    if (n < NN) rowptr[n] = blockoff + sh[tid] - run;
    gridbar(bar, 2 * NB);

    // ---- phase 3: scatter edges into CSR (atomic-free) ----
    for (int e = b * 256 + tid; e < NE; e += NB * 256) {
        int s = e / ESEG;
        int d = dst[e];
        int pos = rowptr[d] + (int)pcnt[(size_t)s * NN + d] + rank[e];
        epack[pos] = make_int2(src[e], __float_as_int(ea[e]));
    }
    gridbar(bar, 3 * NB);

    // ---- phase 4: deg -> dinv/invdeg ----
    const float rw = 1.0f / __uint_as_float(*wmax);
    if (n < NN) {
        int s0 = rowptr[n], s1 = rowptr[n + 1];
        float s = 0.f;
        for (int e = s0; e < s1; ++e) s += __int_as_float(epack[e].y);
        float d = fmaf(s, rw, 1.0f);
        dinv[n] = rsqrtf(d);
        invdeg[n] = 1.0f / d;
    }
    gridbar(bar, 4 * NB);

    // ---- phase 5: epack.y -> layer-invariant coefficient ----
    if (n < NN) {
        float di = dinv[n];
        int s0 = rowptr[n], s1 = rowptr[n + 1];
        for (int e = s0; e < s1; ++e) {
            int2 p = epack[e];
            p.y = __float_as_int(dinv[p.x] * (__int_as_float(p.y) * rw) * di);
            epack[e] = p;
        }
    }
}

// ---------------------------------------------------------------------------
// Aggregation over bf16 H: out = relu( sum coef*H[src] + invdeg[n]*H[n] + b ).
template <int D>
__global__ __launch_bounds__(256) void agg_kernel(const unsigned short* __restrict__ H,
                                                  const int* __restrict__ rowptr,
                                                  const int2* __restrict__ epack,
                                                  const float* __restrict__ invdeg,
                                                  const float* __restrict__ bias,
                                                  unsigned short* __restrict__ out,
                                                  int nNodes) {
    constexpr int LPE = D / 8;    // lanes per edge (16 / 8 / 4)
    constexpr int EPW = 64 / LPE; // edges per iter  (4 / 8 / 16)
    const int lane = threadIdx.x & 63;
    const int n = (blockIdx.x << 2) | (threadIdx.x >> 6);
    if (n >= nNodes) return;
    const int esub = lane / LPE;
    const int f8 = (lane % LPE) * 8;
    const int s0 = rowptr[n];
    const int cnt = rowptr[n + 1] - s0;

    float a[8] = {};
    int kb = 0;
    for (; kb + 2 * EPW <= cnt; kb += 2 * EPW) {
        const int2 pa = epack[s0 + kb + esub];
        const int2 pb = epack[s0 + kb + EPW + esub];
        const uint4 ua = *(const uint4*)(H + (size_t)pa.x * D + f8);
        const uint4 ub = *(const uint4*)(H + (size_t)pb.x * D + f8);
        const float ca = __int_as_float(pa.y);
        const float cb = __int_as_float(pb.y);
        a[0] = fmaf(ca, bflo(ua.x), a[0]); a[1] = fmaf(ca, bfhi(ua.x), a[1]);
        a[2] = fmaf(ca, bflo(ua.y), a[2]); a[3] = fmaf(ca, bfhi(ua.y), a[3]);
        a[4] = fmaf(ca, bflo(ua.z), a[4]); a[5] = fmaf(ca, bfhi(ua.z), a[5]);
        a[6] = fmaf(ca, bflo(ua.w), a[6]); a[7] = fmaf(ca, bfhi(ua.w), a[7]);
        a[0] = fmaf(cb, bflo(ub.x), a[0]); a[1] = fmaf(cb, bfhi(ub.x), a[1]);
        a[2] = fmaf(cb, bflo(ub.y), a[2]); a[3] = fmaf(cb, bfhi(ub.y), a[3]);
        a[4] = fmaf(cb, bflo(ub.z), a[4]); a[5] = fmaf(cb, bfhi(ub.z), a[5]);
        a[6] = fmaf(cb, bflo(ub.w), a[6]); a[7] = fmaf(cb, bfhi(ub.w), a[7]);
    }
    for (; kb < cnt; kb += EPW) {
        const int idx = kb + esub;
        const bool ok = idx < cnt;
        const int2 p = ok ? epack[s0 + idx] : make_int2(n, 0);
        const uint4 u = *(const uint4*)(H + (size_t)p.x * D + f8);
        const float c = ok ? __int_as_float(p.y) : 0.f;
        a[0] = fmaf(c, bflo(u.x), a[0]); a[1] = fmaf(c, bfhi(u.x), a[1]);
        a[2] = fmaf(c, bflo(u.y), a[2]); a[3] = fmaf(c, bfhi(u.y), a[3]);
        a[4] = fmaf(c, bflo(u.z), a[4]); a[5] = fmaf(c, bfhi(u.z), a[5]);
        a[6] = fmaf(c, bflo(u.w), a[6]); a[7] = fmaf(c, bfhi(u.w), a[7]);
    }
#pragma unroll
    for (int off = LPE; off < 64; off <<= 1) {
#pragma unroll
        for (int j = 0; j < 8; ++j) a[j] += __shfl_xor(a[j], off);
    }
    if (esub == 0) {
        const float id = invdeg[n];
        const uint4 un = *(const uint4*)(H + (size_t)n * D + f8);
        const float4 b0 = *(const float4*)(bias + f8);
        const float4 b1 = *(const float4*)(bias + f8 + 4);
        float o[8];
        o[0] = fmaxf(fmaf(id, bflo(un.x), a[0]) + b0.x, 0.f);
        o[1] = fmaxf(fmaf(id, bfhi(un.x), a[1]) + b0.y, 0.f);
        o[2] = fmaxf(fmaf(id, bflo(un.y), a[2]) + b0.z, 0.f);
        o[3] = fmaxf(fmaf(id, bfhi(un.y), a[3]) + b0.w, 0.f);
        o[4] = fmaxf(fmaf(id, bflo(un.z), a[4]) + b1.x, 0.f);
        o[5] = fmaxf(fmaf(id, bfhi(un.z), a[5]) + b1.y, 0.f);
        o[6] = fmaxf(fmaf(id, bflo(un.w), a[6]) + b1.z, 0.f);
        o[7] = fmaxf(fmaf(id, bfhi(un.w), a[7]) + b1.w, 0.f);
        uint4 w;
        w.x = pack2bf(o[0], o[1]);
        w.y = pack2bf(o[2], o[3]);
        w.z = pack2bf(o[4], o[5]);
        w.w = pack2bf(o[6], o[7]);
        *(uint4*)(out + (size_t)n * D + f8) = w;
    }
}

// ---------------------------------------------------------------------------
// Pool (bf16 input): batch SORTED -> one block per graph, binary search range.
__global__ __launch_bounds__(256) void pool2_kernel(const unsigned short* __restrict__ h,
                                                    const int* __restrict__ batch,
                                                    float* __restrict__ pooled, int n) {
    const int g = blockIdx.x;
    int lo = 0, hi = n;
    while (lo < hi) { int m = (lo + hi) >> 1; if (batch[m] < g) lo = m + 1; else hi = m; }
    const int start = lo;
    lo = start; hi = n;
    while (lo < hi) { int m = (lo + hi) >> 1; if (batch[m] < g + 1) lo = m + 1; else hi = m; }
    const int end = lo;

    __shared__ float part[256];
    const int f = threadIdx.x & 31;
    const int r = threadIdx.x >> 5;
    float acc = 0.f;
    for (int i = start + r; i < end; i += 8)
        acc += __uint_as_float((unsigned int)h[(size_t)i * 32 + f] << 16);
    part[threadIdx.x] = acc;
    __syncthreads();
    if (threadIdx.x < 32) {
        float s = 0.f;
#pragma unroll
        for (int q = 0; q < 8; ++q) s += part[q * 32 + f];
        float inv = 1.0f / fmaxf((float)(end - start), 1.0f);
        pooled[g * 32 + f] = s * inv;
    }
}

__global__ void final_kernel(const float* __restrict__ pooled,
                             const float* __restrict__ Wl, const float* __restrict__ bl,
                             float* __restrict__ out) {
    int idx = blockIdx.x * blockDim.x + threadIdx.x;
    int g = idx / OUTD, o = idx - g * OUTD;
    float acc = bl[o];
#pragma unroll
    for (int k = 0; k < 32; ++k)
        acc = fmaf(pooled[g * 32 + k], Wl[k * OUTD + o], acc);
    out[idx] = acc;
}

// ---------------------------------------------------------------------------
extern "C" void kernel_launch(void* const* d_in, const int* in_sizes, int n_in,
                              void* d_out, int out_size, void* d_ws, size_t ws_size,
                              hipStream_t stream) {
    const float* x = (const float*)d_in[0];
    const int* eidx = (const int*)d_in[1];
    const float* ea = (const float*)d_in[2];
    const int* batch = (const int*)d_in[3];
    const float* W1 = (const float*)d_in[4];
    const float* b1 = (const float*)d_in[5];
    const float* W2 = (const float*)d_in[6];
    const float* b2 = (const float*)d_in[7];
    const float* W3 = (const float*)d_in[8];
    const float* b3 = (const float*)d_in[9];
    const float* Wl = (const float*)d_in[10];
    const float* bl = (const float*)d_in[11];
    const int* src = eidx;
    const int* dst = eidx + NE;

    char* p = (char*)d_ws;
    auto take = [&](size_t bytes) {
        char* r = p;
        p += (bytes + 255) & ~(size_t)255;
        return r;
    };
    float* dinv = (float*)take(NN * 4);
    float* invdeg = (float*)take(NN * 4);
    int* rowptr = (int*)take((NN + 1) * 4);
    int* blocksum = (int*)take(256 * 4);
    int2* epack = (int2*)take((size_t)NE * 8);
    float* pooled = (float*)take(NG * 32 * 4);
    unsigned int* wmaxbar = (unsigned int*)take(8);   // [0]=wmax, [1]=bar
    uint4* f1 = (uint4*)take(W1E * 16);
    uint4* f2 = (uint4*)take(W2E * 16);
    uint4* f3 = (uint4*)take(W3E * 16);
    unsigned short* bufA = (unsigned short*)take((size_t)NN * 128 * 2);
    unsigned short* bufB = (unsigned short*)take((size_t)NN * 128 * 2);
    // rank & pcnt alias bufB (12.8 MB): fully consumed by mid_kernel phase 3,
    // which completes before agg1 writes bufB (stream-ordered).
    int* rank = (int*)bufB;                                        // 3.2 MB
    unsigned short* pcnt = (unsigned short*)((char*)bufB + (size_t)NE * 4 + 256);  // 6.4 MB

    unsigned int* wmax = wmaxbar;
    unsigned int* bar = wmaxbar + 1;

    hipMemsetAsync(wmaxbar, 0, 8, stream);

    // W frag tables + wmax (independent of everything downstream of inputs)
    prep_kernel<<<WB + MAXB, 256, 0, stream>>>(W1, W2, W3, f1, f2, f3, ea, wmax);
    // gemm1 (LDS-free MFMA) || hist-rank counting — co-scheduled
    fused1_kernel<<<G1B + HRB, 256, (NTL / 2) * 4, stream>>>(x, f1, bufA, dst, rank, pcnt);
    // comb -> scan -> scat -> deg -> coef in one resident-grid launch
    mid_kernel<<<NB, 256, 0, stream>>>(pcnt, rowptr, blocksum, src, dst, ea, rank,
                                       epack, wmax, dinv, invdeg, bar);

    // layer 1 aggregate (gemm1 already done inside fused1)
    agg_kernel<128><<<(NN + 3) / 4, 256, 0, stream>>>(bufA, rowptr, epack, invdeg, b1, bufB, NN);
    // layer 2: 128->64 (MFMA, LDS-free)
    mfma_gemm_kernel<128, 64, unsigned short><<<G1B, 256, 0, stream>>>(bufB, f2, bufA, NN);
    agg_kernel<64><<<(NN + 3) / 4, 256, 0, stream>>>(bufA, rowptr, epack, invdeg, b2, bufB, NN);
    // layer 3: 64->32 (MFMA, LDS-free)
    mfma_gemm_kernel<64, 32, unsigned short><<<G1B, 256, 0, stream>>>(bufB, f3, bufA, NN);
    agg_kernel<32><<<(NN + 3) / 4, 256, 0, stream>>>(bufA, rowptr, epack, invdeg, b3, bufB, NN);

    pool2_kernel<<<NG, 256, 0, stream>>>(bufB, batch, pooled, NN);
    final_kernel<<<(NG * OUTD) / 256, 256, 0, stream>>>(pooled, Wl, bl, (float*)d_out);
}

// Round 11
// 301.391 us; speedup vs baseline: 1.1636x; 1.1636x over previous
//
#include <hip/hip_runtime.h>
#include <hip/hip_bf16.h>

// Problem constants (fixed by the reference)
#define NN 50000
#define NE 800000
#define NG 64
#define OUTD 768

#define G1B ((NN + 63) / 64)        // 782 gemm blocks (64 rows/block)
#define SSEG 64                     // edge segments
#define TTL 4                       // node tiles (packed u16 counters, 25 KB)
#define ESEG (NE / SSEG)            // 12500 edges / segment
#define NTL (NN / TTL)              // 12500 nodes / tile
#define HRB (SSEG * TTL)            // 256 hist-rank blocks
#define WB 16                       // prep: frag-table blocks
#define MAXB 128                    // prep: max-reduce blocks

// frag-table entry counts (uint4 each)
#define W1E 2048                    // (128/32)*(128/16)*64
#define W2E 1024                    // (128/32)*(64/16)*64
#define W3E 256                     // (64/32)*(32/16)*64

// bf16 helpers: storage is ushort, math is fp32 (RTN-even on store)
__device__ __forceinline__ float bflo(unsigned int u) { return __uint_as_float(u << 16); }
__device__ __forceinline__ float bfhi(unsigned int u) { return __uint_as_float(u & 0xffff0000u); }
__device__ __forceinline__ unsigned short f2bf(float f) {
    unsigned int u = __float_as_uint(f);
    return (unsigned short)((u + 0x7fffu + ((u >> 16) & 1u)) >> 16);
}
__device__ __forceinline__ unsigned int pack2bf(float lo, float hi) {
    return (unsigned int)f2bf(lo) | ((unsigned int)f2bf(hi) << 16);
}

typedef __attribute__((ext_vector_type(8))) short bf16x8;
typedef __attribute__((ext_vector_type(4))) float f32x4;
union FragU { uint4 u4; bf16x8 v; };

// ---------------------------------------------------------------------------
// prep: build bf16 B-fragment tables for W1/W2/W3 (once) + wmax = max(ea).
__global__ __launch_bounds__(256) void prep_kernel(const float* __restrict__ W1,
                                                   const float* __restrict__ W2,
                                                   const float* __restrict__ W3,
                                                   uint4* __restrict__ f1,
                                                   uint4* __restrict__ f2,
                                                   uint4* __restrict__ f3,
                                                   const float* __restrict__ ea,
                                                   unsigned int* wmax) {
    const int b = blockIdx.x;
    if (b < WB) {
        for (int q = b * 256 + threadIdx.x; q < W1E + W2E + W3E; q += WB * 256) {
            const float* W; uint4* F; int N, qq;
            if (q < W1E) { W = W1; F = f1; N = 128; qq = q; }
            else if (q < W1E + W2E) { W = W2; F = f2; N = 64; qq = q - W1E; }
            else { W = W3; F = f3; N = 32; qq = q - W1E - W2E; }
            int lane = qq & 63, fi = qq >> 6;
            int NCT = N / 16, ct = fi % NCT, kc = fi / NCT;
            int col = ct * 16 + (lane & 15);
            int kb = kc * 32 + ((lane >> 4) << 3);
            uint4 w;
            w.x = pack2bf(W[(size_t)(kb + 0) * N + col], W[(size_t)(kb + 1) * N + col]);
            w.y = pack2bf(W[(size_t)(kb + 2) * N + col], W[(size_t)(kb + 3) * N + col]);
            w.z = pack2bf(W[(size_t)(kb + 4) * N + col], W[(size_t)(kb + 5) * N + col]);
            w.w = pack2bf(W[(size_t)(kb + 6) * N + col], W[(size_t)(kb + 7) * N + col]);
            F[qq] = w;
        }
    } else {
        __shared__ float red[256];
        const int bb = b - WB;
        float m = 0.0f;
        for (int i = bb * 256 + threadIdx.x; i < NE; i += MAXB * 256)
            m = fmaxf(m, ea[i]);
        red[threadIdx.x] = m;
        __syncthreads();
        for (int off = 128; off > 0; off >>= 1) {
            if (threadIdx.x < off)
                red[threadIdx.x] = fmaxf(red[threadIdx.x], red[threadIdx.x + off]);
            __syncthreads();
        }
        if (threadIdx.x == 0) atomicMax(wmax, __float_as_uint(red[0]));
    }
}

// ---------------------------------------------------------------------------
// LDS-free MFMA GEMM: Y(bf16) = X @ W via precomputed frag table.
// C/D layout: col=lane&15, row=quad*4+reg  [m89-verified].
template <int K, int N, typename TX>
__device__ __forceinline__ void mfma_gemm_tbl(const TX* __restrict__ X,
                                              const uint4* __restrict__ ftab,
                                              unsigned short* __restrict__ Y,
                                              int nRows, int bx) {
    constexpr int NCT = N / 16;
    constexpr int KS = K / 32;
    const int tid = threadIdx.x;
    const int lane = tid & 63;
    const int wv = tid >> 6;
    const int m = lane & 15;
    const int quad = lane >> 4;
    const int row = bx * 64 + wv * 16 + m;
    const bool rowok = row < nRows;
    const TX* xr = X + (size_t)(rowok ? row : 0) * K;

    f32x4 acc[NCT];
#pragma unroll
    for (int ct = 0; ct < NCT; ++ct) acc[ct] = (f32x4){0.f, 0.f, 0.f, 0.f};

#pragma unroll
    for (int kc = 0; kc < KS; ++kc) {
        const int k0 = kc * 32 + quad * 8;
        FragU a;
        if constexpr (sizeof(TX) == 4) {   // fp32 X -> cvt to bf16
            float4 a0 = make_float4(0.f, 0.f, 0.f, 0.f), a1 = a0;
            if (rowok) {
                a0 = *(const float4*)(xr + k0);
                a1 = *(const float4*)(xr + k0 + 4);
            }
            a.u4 = make_uint4(pack2bf(a0.x, a0.y), pack2bf(a0.z, a0.w),
                              pack2bf(a1.x, a1.y), pack2bf(a1.z, a1.w));
        } else {
            a.u4 = rowok ? *(const uint4*)(xr + k0) : make_uint4(0, 0, 0, 0);
        }
#pragma unroll
        for (int ct = 0; ct < NCT; ++ct) {
            FragU b;
            b.u4 = ftab[(kc * NCT + ct) * 64 + lane];
            acc[ct] = __builtin_amdgcn_mfma_f32_16x16x32_bf16(a.v, b.v, acc[ct], 0, 0, 0);
        }
    }

    const int orowb = bx * 64 + wv * 16 + quad * 4;
#pragma unroll
    for (int ct = 0; ct < NCT; ++ct) {
        int col = ct * 16 + m;
#pragma unroll
        for (int r = 0; r < 4; ++r) {
            int orow = orowb + r;
            if (orow < nRows) Y[(size_t)orow * N + col] = f2bf(acc[ct][r]);
        }
    }
}

template <int K, int N, typename TX>
__global__ __launch_bounds__(256) void mfma_gemm_kernel(const TX* __restrict__ X,
                                                        const uint4* __restrict__ ftab,
                                                        unsigned short* __restrict__ Y,
                                                        int nRows) {
    mfma_gemm_tbl<K, N>(X, ftab, Y, nRows, blockIdx.x);
}

// ---------------------------------------------------------------------------
// fused1: [0,G1B) gemm1 (x fp32 @ W1frag -> bf16, LDS-free); rest: hist-rank
// counting (TTL=4) with packed u16-pair LDS counters (no global atomics).
__global__ __launch_bounds__(256) void fused1_kernel(const float* __restrict__ x,
                                                     const uint4* __restrict__ f1,
                                                     unsigned short* __restrict__ bufA,
                                                     const int* __restrict__ dst,
                                                     int* __restrict__ rank,
                                                     unsigned short* __restrict__ pcnt) {
    extern __shared__ unsigned int lcnt[];   // NTL/2 u32 = 25 KB (u16 pairs)
    const int b = blockIdx.x;
    if (b < G1B) {
        mfma_gemm_tbl<128, 128>(x, f1, bufA, NN, b);
    } else {
        const int b2 = b - G1B;          // 0..HRB-1
        const int seg = b2 >> 2;         // TTL == 4
        const int tile = b2 & 3;
        for (int i = threadIdx.x; i < NTL / 2; i += 256) lcnt[i] = 0;
        __syncthreads();
        const int base = seg * ESEG;
        const int nlo = tile * NTL;
        for (int e = base + threadIdx.x; e < base + ESEG; e += 256) {
            int d = dst[e] - nlo;
            if ((unsigned)d < (unsigned)NTL) {
                unsigned int add = (d & 1) ? 0x10000u : 1u;
                unsigned int old = atomicAdd(&lcnt[d >> 1], add);
                rank[e] = (int)((old >> ((d & 1) * 16)) & 0xffffu);
            }
        }
        __syncthreads();
        unsigned int* prow32 = (unsigned int*)(pcnt + (size_t)seg * NN + nlo);
        for (int i = threadIdx.x; i < NTL / 2; i += 256) prow32[i] = lcnt[i];
    }
}

// ---------------------------------------------------------------------------
// comb: per-node exclusive prefix over segments (in place, u16), total ->
// hist, and fused block-reduction of totals -> blocksum.
__global__ __launch_bounds__(256) void comb_kernel(unsigned short* __restrict__ pcnt,
                                                   int* __restrict__ hist,
                                                   int* __restrict__ blocksum) {
    __shared__ int red[256];
    int n = blockIdx.x * 256 + threadIdx.x;
    int run = 0;
    if (n < NN) {
#pragma unroll
        for (int s = 0; s < SSEG; ++s) {
            size_t idx = (size_t)s * NN + n;
            int v = pcnt[idx];
            pcnt[idx] = (unsigned short)run;
            run += v;
        }
        hist[n] = run;
    }
    red[threadIdx.x] = (n < NN) ? run : 0;
    __syncthreads();
    for (int off = 128; off > 0; off >>= 1) {
        if (threadIdx.x < off) red[threadIdx.x] += red[threadIdx.x + off];
        __syncthreads();
    }
    if (threadIdx.x == 0) blocksum[blockIdx.x] = red[0];
}

__global__ __launch_bounds__(256) void scan2_kernel(const int* __restrict__ blocksum,
                                                    int* __restrict__ blockoff,
                                                    int* __restrict__ total_out, int nb) {
    __shared__ int s[256];
    const int tid = threadIdx.x;
    int v = (tid < nb) ? blocksum[tid] : 0;
    s[tid] = v;
    __syncthreads();
    for (int off = 1; off < 256; off <<= 1) {
        int t = (tid >= off) ? s[tid - off] : 0;
        __syncthreads();
        s[tid] += t;
        __syncthreads();
    }
    if (tid < nb) blockoff[tid] = s[tid] - v;
    if (tid == nb - 1) *total_out = s[tid];
}

__global__ __launch_bounds__(256) void scan3_kernel(const int* __restrict__ hist,
                                                    const int* __restrict__ blockoff,
                                                    int* __restrict__ rowptr, int n) {
    __shared__ int s[256];
    const int tid = threadIdx.x;
    int i = blockIdx.x * 256 + tid;
    int v = (i < n) ? hist[i] : 0;
    s[tid] = v;
    __syncthreads();
    for (int off = 1; off < 256; off <<= 1) {
        int t = (tid >= off) ? s[tid - off] : 0;
        __syncthreads();
        s[tid] += t;
        __syncthreads();
    }
    if (i < n) rowptr[i] = blockoff[blockIdx.x] + s[tid] - v;
}

// ---------------------------------------------------------------------------
// Atomic-free scatter: pos = rowptr[d] + pcnt[seg][d] + rank[e].
__global__ void scat_kernel(const int* __restrict__ src, const int* __restrict__ dst,
                            const float* __restrict__ ea,
                            const int* __restrict__ rowptr,
                            const unsigned short* __restrict__ pcnt,
                            const int* __restrict__ rank,
                            int2* __restrict__ epack, int nE) {
    int e = blockIdx.x * blockDim.x + threadIdx.x;
    if (e >= nE) return;
    int s = e / ESEG;
    int d = dst[e];
    int pos = rowptr[d] + (int)pcnt[(size_t)s * NN + d] + rank[e];
    epack[pos] = make_int2(src[e], __float_as_int(ea[e]));
}

// deg from contiguous CSR segments (no atomics): deg = 1 + rw * sum(ea)
__global__ void deg_kernel(const int2* __restrict__ epack, const int* __restrict__ rowptr,
                           const unsigned int* __restrict__ wmax,
                           float* __restrict__ dinv, float* __restrict__ invdeg, int n) {
    int i = blockIdx.x * blockDim.x + threadIdx.x;
    if (i >= n) return;
    float rw = 1.0f / __uint_as_float(*wmax);
    int s0 = rowptr[i], s1 = rowptr[i + 1];
    float s = 0.f;
    for (int e = s0; e < s1; ++e) s += __int_as_float(epack[e].y);
    float d = fmaf(s, rw, 1.0f);
    dinv[i] = rsqrtf(d);
    invdeg[i] = 1.0f / d;
}

// rewrite epack.y: raw ea -> layer-invariant coefficient
__global__ void coef_kernel(int2* __restrict__ epack, const int* __restrict__ rowptr,
                            const float* __restrict__ dinv,
                            const unsigned int* __restrict__ wmax, int n) {
    int i = blockIdx.x * blockDim.x + threadIdx.x;
    if (i >= n) return;
    float rw = 1.0f / __uint_as_float(*wmax);
    float di = dinv[i];
    int s0 = rowptr[i], s1 = rowptr[i + 1];
    for (int e = s0; e < s1; ++e) {
        int2 p = epack[e];
        p.y = __float_as_int(dinv[p.x] * (__int_as_float(p.y) * rw) * di);
        epack[e] = p;
    }
}

// ---------------------------------------------------------------------------
// Aggregation over bf16 H: out = relu( sum coef*H[src] + invdeg[n]*H[n] + b ).
template <int D>
__global__ __launch_bounds__(256) void agg_kernel(const unsigned short* __restrict__ H,
                                                  const int* __restrict__ rowptr,
                                                  const int2* __restrict__ epack,
                                                  const float* __restrict__ invdeg,
                                                  const float* __restrict__ bias,
                                                  unsigned short* __restrict__ out,
                                                  int nNodes) {
    constexpr int LPE = D / 8;    // lanes per edge (16 / 8 / 4)
    constexpr int EPW = 64 / LPE; // edges per iter  (4 / 8 / 16)
    const int lane = threadIdx.x & 63;
    const int n = (blockIdx.x << 2) | (threadIdx.x >> 6);
    if (n >= nNodes) return;
    const int esub = lane / LPE;
    const int f8 = (lane % LPE) * 8;
    const int s0 = rowptr[n];
    const int cnt = rowptr[n + 1] - s0;

    float a[8] = {};
    int kb = 0;
    for (; kb + 2 * EPW <= cnt; kb += 2 * EPW) {
        const int2 pa = epack[s0 + kb + esub];
        const int2 pb = epack[s0 + kb + EPW + esub];
        const uint4 ua = *(const uint4*)(H + (size_t)pa.x * D + f8);
        const uint4 ub = *(const uint4*)(H + (size_t)pb.x * D + f8);
        const float ca = __int_as_float(pa.y);
        const float cb = __int_as_float(pb.y);
        a[0] = fmaf(ca, bflo(ua.x), a[0]); a[1] = fmaf(ca, bfhi(ua.x), a[1]);
        a[2] = fmaf(ca, bflo(ua.y), a[2]); a[3] = fmaf(ca, bfhi(ua.y), a[3]);
        a[4] = fmaf(ca, bflo(ua.z), a[4]); a[5] = fmaf(ca, bfhi(ua.z), a[5]);
        a[6] = fmaf(ca, bflo(ua.w), a[6]); a[7] = fmaf(ca, bfhi(ua.w), a[7]);
        a[0] = fmaf(cb, bflo(ub.x), a[0]); a[1] = fmaf(cb, bfhi(ub.x), a[1]);
        a[2] = fmaf(cb, bflo(ub.y), a[2]); a[3] = fmaf(cb, bfhi(ub.y), a[3]);
        a[4] = fmaf(cb, bflo(ub.z), a[4]); a[5] = fmaf(cb, bfhi(ub.z), a[5]);
        a[6] = fmaf(cb, bflo(ub.w), a[6]); a[7] = fmaf(cb, bfhi(ub.w), a[7]);
    }
    for (; kb < cnt; kb += EPW) {
        const int idx = kb + esub;
        const bool ok = idx < cnt;
        const int2 p = ok ? epack[s0 + idx] : make_int2(n, 0);
        const uint4 u = *(const uint4*)(H + (size_t)p.x * D + f8);
        const float c = ok ? __int_as_float(p.y) : 0.f;
        a[0] = fmaf(c, bflo(u.x), a[0]); a[1] = fmaf(c, bfhi(u.x), a[1]);
        a[2] = fmaf(c, bflo(u.y), a[2]); a[3] = fmaf(c, bfhi(u.y), a[3]);
        a[4] = fmaf(c, bflo(u.z), a[4]); a[5] = fmaf(c, bfhi(u.z), a[5]);
        a[6] = fmaf(c, bflo(u.w), a[6]); a[7] = fmaf(c, bfhi(u.w), a[7]);
    }
#pragma unroll
    for (int off = LPE; off < 64; off <<= 1) {
#pragma unroll
        for (int j = 0; j < 8; ++j) a[j] += __shfl_xor(a[j], off);
    }
    if (esub == 0) {
        const float id = invdeg[n];
        const uint4 un = *(const uint4*)(H + (size_t)n * D + f8);
        const float4 b0 = *(const float4*)(bias + f8);
        const float4 b1 = *(const float4*)(bias + f8 + 4);
        float o[8];
        o[0] = fmaxf(fmaf(id, bflo(un.x), a[0]) + b0.x, 0.f);
        o[1] = fmaxf(fmaf(id, bfhi(un.x), a[1]) + b0.y, 0.f);
        o[2] = fmaxf(fmaf(id, bflo(un.y), a[2]) + b0.z, 0.f);
        o[3] = fmaxf(fmaf(id, bfhi(un.y), a[3]) + b0.w, 0.f);
        o[4] = fmaxf(fmaf(id, bflo(un.z), a[4]) + b1.x, 0.f);
        o[5] = fmaxf(fmaf(id, bfhi(un.z), a[5]) + b1.y, 0.f);
        o[6] = fmaxf(fmaf(id, bflo(un.w), a[6]) + b1.z, 0.f);
        o[7] = fmaxf(fmaf(id, bfhi(un.w), a[7]) + b1.w, 0.f);
        uint4 w;
        w.x = pack2bf(o[0], o[1]);
        w.y = pack2bf(o[2], o[3]);
        w.z = pack2bf(o[4], o[5]);
        w.w = pack2bf(o[6], o[7]);
        *(uint4*)(out + (size_t)n * D + f8) = w;
    }
}

// ---------------------------------------------------------------------------
// Pool (bf16 input): batch SORTED -> one block per graph, binary search range.
__global__ __launch_bounds__(256) void pool2_kernel(const unsigned short* __restrict__ h,
                                                    const int* __restrict__ batch,
                                                    float* __restrict__ pooled, int n) {
    const int g = blockIdx.x;
    int lo = 0, hi = n;
    while (lo < hi) { int m = (lo + hi) >> 1; if (batch[m] < g) lo = m + 1; else hi = m; }
    const int start = lo;
    lo = start; hi = n;
    while (lo < hi) { int m = (lo + hi) >> 1; if (batch[m] < g + 1) lo = m + 1; else hi = m; }
    const int end = lo;

    __shared__ float part[256];
    const int f = threadIdx.x & 31;
    const int r = threadIdx.x >> 5;
    float acc = 0.f;
    for (int i = start + r; i < end; i += 8)
        acc += __uint_as_float((unsigned int)h[(size_t)i * 32 + f] << 16);
    part[threadIdx.x] = acc;
    __syncthreads();
    if (threadIdx.x < 32) {
        float s = 0.f;
#pragma unroll
        for (int q = 0; q < 8; ++q) s += part[q * 32 + f];
        float inv = 1.0f / fmaxf((float)(end - start), 1.0f);
        pooled[g * 32 + f] = s * inv;
    }
}

__global__ void final_kernel(const float* __restrict__ pooled,
                             const float* __restrict__ Wl, const float* __restrict__ bl,
                             float* __restrict__ out) {
    int idx = blockIdx.x * blockDim.x + threadIdx.x;
    int g = idx / OUTD, o = idx - g * OUTD;
    float acc = bl[o];
#pragma unroll
    for (int k = 0; k < 32; ++k)
        acc = fmaf(pooled[g * 32 + k], Wl[k * OUTD + o], acc);
    out[idx] = acc;
}

// ---------------------------------------------------------------------------
extern "C" void kernel_launch(void* const* d_in, const int* in_sizes, int n_in,
                              void* d_out, int out_size, void* d_ws, size_t ws_size,
                              hipStream_t stream) {
    const float* x = (const float*)d_in[0];
    const int* eidx = (const int*)d_in[1];
    const float* ea = (const float*)d_in[2];
    const int* batch = (const int*)d_in[3];
    const float* W1 = (const float*)d_in[4];
    const float* b1 = (const float*)d_in[5];
    const float* W2 = (const float*)d_in[6];
    const float* b2 = (const float*)d_in[7];
    const float* W3 = (const float*)d_in[8];
    const float* b3 = (const float*)d_in[9];
    const float* Wl = (const float*)d_in[10];
    const float* bl = (const float*)d_in[11];
    const int* src = eidx;
    const int* dst = eidx + NE;

    char* p = (char*)d_ws;
    auto take = [&](size_t bytes) {
        char* r = p;
        p += (bytes + 255) & ~(size_t)255;
        return r;
    };
    float* dinv = (float*)take(NN * 4);
    float* invdeg = (float*)take(NN * 4);
    int* hist = (int*)take(NN * 4);
    int* rowptr = (int*)take((NN + 1) * 4);
    int* blocksum = (int*)take(256 * 4);
    int* blockoff = (int*)take(256 * 4);
    int2* epack = (int2*)take((size_t)NE * 8);
    float* pooled = (float*)take(NG * 32 * 4);
    unsigned int* wmax = (unsigned int*)take(4);
    uint4* f1 = (uint4*)take(W1E * 16);
    uint4* f2 = (uint4*)take(W2E * 16);
    uint4* f3 = (uint4*)take(W3E * 16);
    unsigned short* bufA = (unsigned short*)take((size_t)NN * 128 * 2);
    unsigned short* bufB = (unsigned short*)take((size_t)NN * 128 * 2);
    // rank & pcnt alias bufB (12.8 MB): fully consumed by scat_kernel,
    // which completes before agg1 writes bufB (stream-ordered).
    int* rank = (int*)bufB;                                        // 3.2 MB
    unsigned short* pcnt = (unsigned short*)((char*)bufB + (size_t)NE * 4 + 256);  // 6.4 MB

    const int nblk = (NN + 255) / 256;   // 196
    const int eblk = (NE + 255) / 256;   // 3125

    hipMemsetAsync(wmax, 0, 4, stream);

    // W frag tables + wmax
    prep_kernel<<<WB + MAXB, 256, 0, stream>>>(W1, W2, W3, f1, f2, f3, ea, wmax);
    // gemm1 (LDS-free MFMA) || hist-rank counting — co-scheduled
    fused1_kernel<<<G1B + HRB, 256, (NTL / 2) * 4, stream>>>(x, f1, bufA, dst, rank, pcnt);
    // mid-section: wide, separate kernels (grid-resident fusion regressed — R10)
    comb_kernel<<<nblk, 256, 0, stream>>>(pcnt, hist, blocksum);
    scan2_kernel<<<1, 256, 0, stream>>>(blocksum, blockoff, &rowptr[NN], nblk);
    scan3_kernel<<<nblk, 256, 0, stream>>>(hist, blockoff, rowptr, NN);
    scat_kernel<<<eblk, 256, 0, stream>>>(src, dst, ea, rowptr, pcnt, rank, epack, NE);
    deg_kernel<<<nblk, 256, 0, stream>>>(epack, rowptr, wmax, dinv, invdeg, NN);
    coef_kernel<<<nblk, 256, 0, stream>>>(epack, rowptr, dinv, wmax, NN);

    // layer 1 aggregate (gemm1 already done inside fused1)
    agg_kernel<128><<<(NN + 3) / 4, 256, 0, stream>>>(bufA, rowptr, epack, invdeg, b1, bufB, NN);
    // layer 2: 128->64 (MFMA, LDS-free)
    mfma_gemm_kernel<128, 64, unsigned short><<<G1B, 256, 0, stream>>>(bufB, f2, bufA, NN);
    agg_kernel<64><<<(NN + 3) / 4, 256, 0, stream>>>(bufA, rowptr, epack, invdeg, b2, bufB, NN);
    // layer 3: 64->32 (MFMA, LDS-free)
    mfma_gemm_kernel<64, 32, unsigned short><<<G1B, 256, 0, stream>>>(bufB, f3, bufA, NN);
    agg_kernel<32><<<(NN + 3) / 4, 256, 0, stream>>>(bufA, rowptr, epack, invdeg, b3, bufB, NN);

    pool2_kernel<<<NG, 256, 0, stream>>>(bufB, batch, pooled, NN);
    final_kernel<<<(NG * OUTD) / 256, 256, 0, stream>>>(pooled, Wl, bl, (float*)d_out);
}

// Round 12
// 301.061 us; speedup vs baseline: 1.1649x; 1.0011x over previous
//
#include <hip/hip_runtime.h>
#include <hip/hip_bf16.h>

// Problem constants (fixed by the reference)
#define NN 50000
#define NE 800000
#define NG 64
#define OUTD 768

#define G1B ((NN + 63) / 64)        // 782 gemm blocks (64 rows/block)
#define SSEG 64                     // edge segments
#define TTL 4                       // node tiles (packed u16 counters, 25 KB)
#define ESEG (NE / SSEG)            // 12500 edges / segment
#define NTL (NN / TTL)              // 12500 nodes / tile
#define HRB (SSEG * TTL)            // 256 hist-rank blocks
#define WB 16                       // prep: frag-table blocks
#define MAXB 128                    // prep: max-reduce blocks
#define NB 196                      // comb_scan blocks (1/CU, co-resident)

// frag-table entry counts (uint4 each)
#define W1E 2048                    // (128/32)*(128/16)*64
#define W2E 1024                    // (128/32)*(64/16)*64
#define W3E 256                     // (64/32)*(32/16)*64

// bf16 helpers: storage is ushort, math is fp32 (RTN-even on store)
__device__ __forceinline__ float bflo(unsigned int u) { return __uint_as_float(u << 16); }
__device__ __forceinline__ float bfhi(unsigned int u) { return __uint_as_float(u & 0xffff0000u); }
__device__ __forceinline__ unsigned short f2bf(float f) {
    unsigned int u = __float_as_uint(f);
    return (unsigned short)((u + 0x7fffu + ((u >> 16) & 1u)) >> 16);
}
__device__ __forceinline__ unsigned int pack2bf(float lo, float hi) {
    return (unsigned int)f2bf(lo) | ((unsigned int)f2bf(hi) << 16);
}

typedef __attribute__((ext_vector_type(8))) short bf16x8;
typedef __attribute__((ext_vector_type(4))) float f32x4;
union FragU { uint4 u4; bf16x8 v; };

// ---------------------------------------------------------------------------
// prep: build bf16 B-fragment tables for W1/W2/W3 (once) + wmax = max(ea).
__global__ __launch_bounds__(256) void prep_kernel(const float* __restrict__ W1,
                                                   const float* __restrict__ W2,
                                                   const float* __restrict__ W3,
                                                   uint4* __restrict__ f1,
                                                   uint4* __restrict__ f2,
                                                   uint4* __restrict__ f3,
                                                   const float* __restrict__ ea,
                                                   unsigned int* wmax) {
    const int b = blockIdx.x;
    if (b < WB) {
        for (int q = b * 256 + threadIdx.x; q < W1E + W2E + W3E; q += WB * 256) {
            const float* W; uint4* F; int N, qq;
            if (q < W1E) { W = W1; F = f1; N = 128; qq = q; }
            else if (q < W1E + W2E) { W = W2; F = f2; N = 64; qq = q - W1E; }
            else { W = W3; F = f3; N = 32; qq = q - W1E - W2E; }
            int lane = qq & 63, fi = qq >> 6;
            int NCT = N / 16, ct = fi % NCT, kc = fi / NCT;
            int col = ct * 16 + (lane & 15);
            int kb = kc * 32 + ((lane >> 4) << 3);
            uint4 w;
            w.x = pack2bf(W[(size_t)(kb + 0) * N + col], W[(size_t)(kb + 1) * N + col]);
            w.y = pack2bf(W[(size_t)(kb + 2) * N + col], W[(size_t)(kb + 3) * N + col]);
            w.z = pack2bf(W[(size_t)(kb + 4) * N + col], W[(size_t)(kb + 5) * N + col]);
            w.w = pack2bf(W[(size_t)(kb + 6) * N + col], W[(size_t)(kb + 7) * N + col]);
            F[qq] = w;
        }
    } else {
        __shared__ float red[256];
        const int bb = b - WB;
        float m = 0.0f;
        for (int i = bb * 256 + threadIdx.x; i < NE; i += MAXB * 256)
            m = fmaxf(m, ea[i]);
        red[threadIdx.x] = m;
        __syncthreads();
        for (int off = 128; off > 0; off >>= 1) {
            if (threadIdx.x < off)
                red[threadIdx.x] = fmaxf(red[threadIdx.x], red[threadIdx.x + off]);
            __syncthreads();
        }
        if (threadIdx.x == 0) atomicMax(wmax, __float_as_uint(red[0]));
    }
}

// ---------------------------------------------------------------------------
// LDS-free MFMA GEMM: Y(bf16) = scale? dinv[row]*(X@W) : (X@W), frag table B.
// C/D layout: col=lane&15, row=quad*4+reg  [m89-verified].
template <int K, int N, bool SCALE, typename TX>
__device__ __forceinline__ void mfma_gemm_tbl(const TX* __restrict__ X,
                                              const uint4* __restrict__ ftab,
                                              unsigned short* __restrict__ Y,
                                              const float* __restrict__ dinv,
                                              int nRows, int bx) {
    constexpr int NCT = N / 16;
    constexpr int KS = K / 32;
    const int tid = threadIdx.x;
    const int lane = tid & 63;
    const int wv = tid >> 6;
    const int m = lane & 15;
    const int quad = lane >> 4;
    const int row = bx * 64 + wv * 16 + m;
    const bool rowok = row < nRows;
    const TX* xr = X + (size_t)(rowok ? row : 0) * K;

    f32x4 acc[NCT];
#pragma unroll
    for (int ct = 0; ct < NCT; ++ct) acc[ct] = (f32x4){0.f, 0.f, 0.f, 0.f};

#pragma unroll
    for (int kc = 0; kc < KS; ++kc) {
        const int k0 = kc * 32 + quad * 8;
        FragU a;
        if constexpr (sizeof(TX) == 4) {   // fp32 X -> cvt to bf16
            float4 a0 = make_float4(0.f, 0.f, 0.f, 0.f), a1 = a0;
            if (rowok) {
                a0 = *(const float4*)(xr + k0);
                a1 = *(const float4*)(xr + k0 + 4);
            }
            a.u4 = make_uint4(pack2bf(a0.x, a0.y), pack2bf(a0.z, a0.w),
                              pack2bf(a1.x, a1.y), pack2bf(a1.z, a1.w));
        } else {
            a.u4 = rowok ? *(const uint4*)(xr + k0) : make_uint4(0, 0, 0, 0);
        }
#pragma unroll
        for (int ct = 0; ct < NCT; ++ct) {
            FragU b;
            b.u4 = ftab[(kc * NCT + ct) * 64 + lane];
            acc[ct] = __builtin_amdgcn_mfma_f32_16x16x32_bf16(a.v, b.v, acc[ct], 0, 0, 0);
        }
    }

    const int orowb = bx * 64 + wv * 16 + quad * 4;
    float dsc[4];
#pragma unroll
    for (int r = 0; r < 4; ++r)
        dsc[r] = SCALE ? ((orowb + r < nRows) ? dinv[orowb + r] : 1.0f) : 1.0f;
#pragma unroll
    for (int ct = 0; ct < NCT; ++ct) {
        int col = ct * 16 + m;
#pragma unroll
        for (int r = 0; r < 4; ++r) {
            int orow = orowb + r;
            if (orow < nRows) Y[(size_t)orow * N + col] = f2bf(dsc[r] * acc[ct][r]);
        }
    }
}

template <int K, int N, bool SCALE, typename TX>
__global__ __launch_bounds__(256) void mfma_gemm_kernel(const TX* __restrict__ X,
                                                        const uint4* __restrict__ ftab,
                                                        unsigned short* __restrict__ Y,
                                                        const float* __restrict__ dinv,
                                                        int nRows) {
    mfma_gemm_tbl<K, N, SCALE>(X, ftab, Y, dinv, nRows, blockIdx.x);
}

// ---------------------------------------------------------------------------
// fused1: [0,G1B) gemm1 (x fp32 @ W1frag -> bf16 UNSCALED; deg_scale applies
// dinv later); rest: hist-rank counting (TTL=4, packed u16 LDS counters).
__global__ __launch_bounds__(256) void fused1_kernel(const float* __restrict__ x,
                                                     const uint4* __restrict__ f1,
                                                     unsigned short* __restrict__ bufA,
                                                     const int* __restrict__ dst,
                                                     int* __restrict__ rank,
                                                     unsigned short* __restrict__ pcnt) {
    extern __shared__ unsigned int lcnt[];   // NTL/2 u32 = 25 KB (u16 pairs)
    const int b = blockIdx.x;
    if (b < G1B) {
        mfma_gemm_tbl<128, 128, false>(x, f1, bufA, nullptr, NN, b);
    } else {
        const int b2 = b - G1B;          // 0..HRB-1
        const int seg = b2 >> 2;         // TTL == 4
        const int tile = b2 & 3;
        for (int i = threadIdx.x; i < NTL / 2; i += 256) lcnt[i] = 0;
        __syncthreads();
        const int base = seg * ESEG;
        const int nlo = tile * NTL;
        for (int e = base + threadIdx.x; e < base + ESEG; e += 256) {
            int d = dst[e] - nlo;
            if ((unsigned)d < (unsigned)NTL) {
                unsigned int add = (d & 1) ? 0x10000u : 1u;
                unsigned int old = atomicAdd(&lcnt[d >> 1], add);
                rank[e] = (int)((old >> ((d & 1) * 16)) & 0xffffu);
            }
        }
        __syncthreads();
        unsigned int* prow32 = (unsigned int*)(pcnt + (size_t)seg * NN + nlo);
        for (int i = threadIdx.x; i < NTL / 2; i += 256) prow32[i] = lcnt[i];
    }
}

// ---------------------------------------------------------------------------
// Grid barrier (R10 pattern — correctness-verified there; NB=196 <= 256 CUs).
__device__ __forceinline__ void gridbar(unsigned int* bar, unsigned int target) {
    __syncthreads();
    if (threadIdx.x == 0) {
        __hip_atomic_fetch_add(bar, 1u, __ATOMIC_ACQ_REL, __HIP_MEMORY_SCOPE_AGENT);
        while (__hip_atomic_load(bar, __ATOMIC_ACQUIRE, __HIP_MEMORY_SCOPE_AGENT) < target)
            __builtin_amdgcn_s_sleep(2);
    }
    __syncthreads();
}

// comb_scan: per-node seg-prefix (in place) + full rowptr scan, one launch.
__global__ __launch_bounds__(256) void comb_scan_kernel(unsigned short* __restrict__ pcnt,
                                                        int* __restrict__ rowptr,
                                                        int* __restrict__ blocksum,
                                                        unsigned int* bar) {
    __shared__ int sh[256];
    const int tid = threadIdx.x;
    const int b = blockIdx.x;
    const int n = b * 256 + tid;

    // phase 1: exclusive prefix over segments for node n
    int run = 0;
    if (n < NN) {
#pragma unroll
        for (int s = 0; s < SSEG; ++s) {
            size_t idx = (size_t)s * NN + n;
            int v = pcnt[idx];
            pcnt[idx] = (unsigned short)run;
            run += v;
        }
    }
    sh[tid] = run;
    __syncthreads();
    for (int off = 128; off > 0; off >>= 1) {
        if (tid < off) sh[tid] += sh[tid + off];
        __syncthreads();
    }
    if (tid == 0) blocksum[b] = sh[0];
    gridbar(bar, NB);

    // phase 2: rowptr = global exclusive scan
    int v2 = (tid < NB) ? blocksum[tid] : 0;
    __syncthreads();
    sh[tid] = v2;
    __syncthreads();
    for (int off = 1; off < 256; off <<= 1) {
        int t = (tid >= off) ? sh[tid - off] : 0;
        __syncthreads();
        sh[tid] += t;
        __syncthreads();
    }
    const int blockoff = (b > 0) ? sh[b - 1] : 0;
    if (b == 0 && tid == 0) rowptr[NN] = sh[NB - 1];
    __syncthreads();
    sh[tid] = run;
    __syncthreads();
    for (int off = 1; off < 256; off <<= 1) {
        int t = (tid >= off) ? sh[tid - off] : 0;
        __syncthreads();
        sh[tid] += t;
        __syncthreads();
    }
    if (n < NN) rowptr[n] = blockoff + sh[tid] - run;
}

// ---------------------------------------------------------------------------
// Atomic-free scatter: pos = rowptr[d] + pcnt[seg][d] + rank[e].
// Stores {src, ea*rw} — NO dinv factors (folded into features).
__global__ void scat_kernel(const int* __restrict__ src, const int* __restrict__ dst,
                            const float* __restrict__ ea,
                            const int* __restrict__ rowptr,
                            const unsigned short* __restrict__ pcnt,
                            const int* __restrict__ rank,
                            const unsigned int* __restrict__ wmax,
                            int2* __restrict__ epack, int nE) {
    int e = blockIdx.x * blockDim.x + threadIdx.x;
    if (e >= nE) return;
    float rw = 1.0f / __uint_as_float(*wmax);
    int s = e / ESEG;
    int d = dst[e];
    int pos = rowptr[d] + (int)pcnt[(size_t)s * NN + d] + rank[e];
    epack[pos] = make_int2(src[e], __float_as_int(ea[e] * rw));
}

// deg_scale: dinv[n] = rsqrt(1 + sum epack.y) ; then scale bufA rows in place
// (H1' = dinv * H1). Block owns 256 contiguous nodes/rows.
__global__ __launch_bounds__(256) void deg_scale_kernel(const int2* __restrict__ epack,
                                                        const int* __restrict__ rowptr,
                                                        float* __restrict__ dinv,
                                                        unsigned short* __restrict__ bufA) {
    __shared__ float sdinv[256];
    const int tid = threadIdx.x;
    const int b = blockIdx.x;
    const int n = b * 256 + tid;
    float di = 1.0f;
    if (n < NN) {
        int s0 = rowptr[n], s1 = rowptr[n + 1];
        float s = 1.0f;   // self-loop weight
        for (int e = s0; e < s1; ++e) s += __int_as_float(epack[e].y);
        di = rsqrtf(s);
        dinv[n] = di;
    }
    sdinv[tid] = di;
    __syncthreads();
    // scale this block's 256 rows (128 bf16 each = 16 uint4) by sdinv[row]
    const int nrows = min(256, NN - b * 256);
    uint4* rows = (uint4*)bufA + (size_t)b * 256 * 16;
    for (int q = tid; q < nrows * 16; q += 256) {
        const float d = sdinv[q >> 4];
        uint4 u = rows[q];
        u.x = pack2bf(d * bflo(u.x), d * bfhi(u.x));
        u.y = pack2bf(d * bflo(u.y), d * bfhi(u.y));
        u.z = pack2bf(d * bflo(u.z), d * bfhi(u.z));
        u.w = pack2bf(d * bflo(u.w), d * bfhi(u.w));
        rows[q] = u;
    }
}

// ---------------------------------------------------------------------------
// Aggregation over bf16 H' (= dinv*H): out = relu( dinv[n]*(S + H'[n]) + b ),
// S = sum w_e * H'[src]. One node/wave, 16B (8 bf16)/lane, fp32 accumulate.
template <int D>
__global__ __launch_bounds__(256) void agg_kernel(const unsigned short* __restrict__ H,
                                                  const int* __restrict__ rowptr,
                                                  const int2* __restrict__ epack,
                                                  const float* __restrict__ dinv,
                                                  const float* __restrict__ bias,
                                                  unsigned short* __restrict__ out,
                                                  int nNodes) {
    constexpr int LPE = D / 8;    // lanes per edge (16 / 8 / 4)
    constexpr int EPW = 64 / LPE; // edges per iter  (4 / 8 / 16)
    const int lane = threadIdx.x & 63;
    const int n = (blockIdx.x << 2) | (threadIdx.x >> 6);
    if (n >= nNodes) return;
    const int esub = lane / LPE;
    const int f8 = (lane % LPE) * 8;
    const int s0 = rowptr[n];
    const int cnt = rowptr[n + 1] - s0;

    float a[8] = {};
    int kb = 0;
    for (; kb + 2 * EPW <= cnt; kb += 2 * EPW) {
        const int2 pa = epack[s0 + kb + esub];
        const int2 pb = epack[s0 + kb + EPW + esub];
        const uint4 ua = *(const uint4*)(H + (size_t)pa.x * D + f8);
        const uint4 ub = *(const uint4*)(H + (size_t)pb.x * D + f8);
        const float ca = __int_as_float(pa.y);
        const float cb = __int_as_float(pb.y);
        a[0] = fmaf(ca, bflo(ua.x), a[0]); a[1] = fmaf(ca, bfhi(ua.x), a[1]);
        a[2] = fmaf(ca, bflo(ua.y), a[2]); a[3] = fmaf(ca, bfhi(ua.y), a[3]);
        a[4] = fmaf(ca, bflo(ua.z), a[4]); a[5] = fmaf(ca, bfhi(ua.z), a[5]);
        a[6] = fmaf(ca, bflo(ua.w), a[6]); a[7] = fmaf(ca, bfhi(ua.w), a[7]);
        a[0] = fmaf(cb, bflo(ub.x), a[0]); a[1] = fmaf(cb, bfhi(ub.x), a[1]);
        a[2] = fmaf(cb, bflo(ub.y), a[2]); a[3] = fmaf(cb, bfhi(ub.y), a[3]);
        a[4] = fmaf(cb, bflo(ub.z), a[4]); a[5] = fmaf(cb, bfhi(ub.z), a[5]);
        a[6] = fmaf(cb, bflo(ub.w), a[6]); a[7] = fmaf(cb, bfhi(ub.w), a[7]);
    }
    for (; kb < cnt; kb += EPW) {
        const int idx = kb + esub;
        const bool ok = idx < cnt;
        const int2 p = ok ? epack[s0 + idx] : make_int2(n, 0);
        const uint4 u = *(const uint4*)(H + (size_t)p.x * D + f8);
        const float c = ok ? __int_as_float(p.y) : 0.f;
        a[0] = fmaf(c, bflo(u.x), a[0]); a[1] = fmaf(c, bfhi(u.x), a[1]);
        a[2] = fmaf(c, bflo(u.y), a[2]); a[3] = fmaf(c, bfhi(u.y), a[3]);
        a[4] = fmaf(c, bflo(u.z), a[4]); a[5] = fmaf(c, bfhi(u.z), a[5]);
        a[6] = fmaf(c, bflo(u.w), a[6]); a[7] = fmaf(c, bfhi(u.w), a[7]);
    }
#pragma unroll
    for (int off = LPE; off < 64; off <<= 1) {
#pragma unroll
        for (int j = 0; j < 8; ++j) a[j] += __shfl_xor(a[j], off);
    }
    if (esub == 0) {
        const float di = dinv[n];
        const uint4 un = *(const uint4*)(H + (size_t)n * D + f8);
        const float4 b0 = *(const float4*)(bias + f8);
        const float4 b1 = *(const float4*)(bias + f8 + 4);
        float o[8];
        o[0] = fmaxf(fmaf(di, a[0] + bflo(un.x), b0.x), 0.f);
        o[1] = fmaxf(fmaf(di, a[1] + bfhi(un.x), b0.y), 0.f);
        o[2] = fmaxf(fmaf(di, a[2] + bflo(un.y), b0.z), 0.f);
        o[3] = fmaxf(fmaf(di, a[3] + bfhi(un.y), b0.w), 0.f);
        o[4] = fmaxf(fmaf(di, a[4] + bflo(un.z), b1.x), 0.f);
        o[5] = fmaxf(fmaf(di, a[5] + bfhi(un.z), b1.y), 0.f);
        o[6] = fmaxf(fmaf(di, a[6] + bflo(un.w), b1.z), 0.f);
        o[7] = fmaxf(fmaf(di, a[7] + bfhi(un.w), b1.w), 0.f);
        uint4 w;
        w.x = pack2bf(o[0], o[1]);
        w.y = pack2bf(o[2], o[3]);
        w.z = pack2bf(o[4], o[5]);
        w.w = pack2bf(o[6], o[7]);
        *(uint4*)(out + (size_t)n * D + f8) = w;
    }
}

// ---------------------------------------------------------------------------
// Pool (bf16 input): batch SORTED -> one block per graph, binary search range.
__global__ __launch_bounds__(256) void pool2_kernel(const unsigned short* __restrict__ h,
                                                    const int* __restrict__ batch,
                                                    float* __restrict__ pooled, int n) {
    const int g = blockIdx.x;
    int lo = 0, hi = n;
    while (lo < hi) { int m = (lo + hi) >> 1; if (batch[m] < g) lo = m + 1; else hi = m; }
    const int start = lo;
    lo = start; hi = n;
    while (lo < hi) { int m = (lo + hi) >> 1; if (batch[m] < g + 1) lo = m + 1; else hi = m; }
    const int end = lo;

    __shared__ float part[256];
    const int f = threadIdx.x & 31;
    const int r = threadIdx.x >> 5;
    float acc = 0.f;
    for (int i = start + r; i < end; i += 8)
        acc += __uint_as_float((unsigned int)h[(size_t)i * 32 + f] << 16);
    part[threadIdx.x] = acc;
    __syncthreads();
    if (threadIdx.x < 32) {
        float s = 0.f;
#pragma unroll
        for (int q = 0; q < 8; ++q) s += part[q * 32 + f];
        float inv = 1.0f / fmaxf((float)(end - start), 1.0f);
        pooled[g * 32 + f] = s * inv;
    }
}

__global__ void final_kernel(const float* __restrict__ pooled,
                             const float* __restrict__ Wl, const float* __restrict__ bl,
                             float* __restrict__ out) {
    int idx = blockIdx.x * blockDim.x + threadIdx.x;
    int g = idx / OUTD, o = idx - g * OUTD;
    float acc = bl[o];
#pragma unroll
    for (int k = 0; k < 32; ++k)
        acc = fmaf(pooled[g * 32 + k], Wl[k * OUTD + o], acc);
    out[idx] = acc;
}

// ---------------------------------------------------------------------------
extern "C" void kernel_launch(void* const* d_in, const int* in_sizes, int n_in,
                              void* d_out, int out_size, void* d_ws, size_t ws_size,
                              hipStream_t stream) {
    const float* x = (const float*)d_in[0];
    const int* eidx = (const int*)d_in[1];
    const float* ea = (const float*)d_in[2];
    const int* batch = (const int*)d_in[3];
    const float* W1 = (const float*)d_in[4];
    const float* b1 = (const float*)d_in[5];
    const float* W2 = (const float*)d_in[6];
    const float* b2 = (const float*)d_in[7];
    const float* W3 = (const float*)d_in[8];
    const float* b3 = (const float*)d_in[9];
    const float* Wl = (const float*)d_in[10];
    const float* bl = (const float*)d_in[11];
    const int* src = eidx;
    const int* dst = eidx + NE;

    char* p = (char*)d_ws;
    auto take = [&](size_t bytes) {
        char* r = p;
        p += (bytes + 255) & ~(size_t)255;
        return r;
    };
    float* dinv = (float*)take(NN * 4);
    int* rowptr = (int*)take((NN + 1) * 4);
    int* blocksum = (int*)take(256 * 4);
    int2* epack = (int2*)take((size_t)NE * 8);
    float* pooled = (float*)take(NG * 32 * 4);
    unsigned int* wmaxbar = (unsigned int*)take(8);   // [0]=wmax, [1]=bar
    uint4* f1 = (uint4*)take(W1E * 16);
    uint4* f2 = (uint4*)take(W2E * 16);
    uint4* f3 = (uint4*)take(W3E * 16);
    unsigned short* bufA = (unsigned short*)take((size_t)NN * 128 * 2);
    unsigned short* bufB = (unsigned short*)take((size_t)NN * 128 * 2);
    // rank & pcnt alias bufB (12.8 MB): fully consumed by scat_kernel,
    // which completes before agg1 writes bufB (stream-ordered).
    int* rank = (int*)bufB;                                        // 3.2 MB
    unsigned short* pcnt = (unsigned short*)((char*)bufB + (size_t)NE * 4 + 256);  // 6.4 MB

    unsigned int* wmax = wmaxbar;
    unsigned int* bar = wmaxbar + 1;

    const int nblk = (NN + 255) / 256;   // 196
    const int eblk = (NE + 255) / 256;   // 3125

    hipMemsetAsync(wmaxbar, 0, 8, stream);

    // W frag tables + wmax
    prep_kernel<<<WB + MAXB, 256, 0, stream>>>(W1, W2, W3, f1, f2, f3, ea, wmax);
    // gemm1 (LDS-free MFMA, unscaled) || hist-rank counting — co-scheduled
    fused1_kernel<<<G1B + HRB, 256, (NTL / 2) * 4, stream>>>(x, f1, bufA, dst, rank, pcnt);
    // seg-prefix + rowptr scan in one launch (196 co-resident blocks, 1 gridbar)
    comb_scan_kernel<<<NB, 256, 0, stream>>>(pcnt, rowptr, blocksum, bar);
    // scatter: epack = {src, ea*rw}
    scat_kernel<<<eblk, 256, 0, stream>>>(src, dst, ea, rowptr, pcnt, rank, wmax, epack, NE);
    // dinv + in-place H1' = dinv*H1
    deg_scale_kernel<<<nblk, 256, 0, stream>>>(epack, rowptr, dinv, bufA);

    // layer 1 aggregate
    agg_kernel<128><<<(NN + 3) / 4, 256, 0, stream>>>(bufA, rowptr, epack, dinv, b1, bufB, NN);
    // layer 2: 128->64 (MFMA, epilogue applies dinv -> H2')
    mfma_gemm_kernel<128, 64, true, unsigned short>
        <<<G1B, 256, 0, stream>>>(bufB, f2, bufA, dinv, NN);
    agg_kernel<64><<<(NN + 3) / 4, 256, 0, stream>>>(bufA, rowptr, epack, dinv, b2, bufB, NN);
    // layer 3: 64->32 (MFMA, epilogue applies dinv -> H3')
    mfma_gemm_kernel<64, 32, true, unsigned short>
        <<<G1B, 256, 0, stream>>>(bufB, f3, bufA, dinv, NN);
    agg_kernel<32><<<(NN + 3) / 4, 256, 0, stream>>>(bufA, rowptr, epack, dinv, b3, bufB, NN);

    pool2_kernel<<<NG, 256, 0, stream>>>(bufB, batch, pooled, NN);
    final_kernel<<<(NG * OUTD) / 256, 256, 0, stream>>>(pooled, Wl, bl, (float*)d_out);
}